// Round 3
// baseline (477.763 us; speedup 1.0000x reference)
//
#include <hip/hip_runtime.h>
#include <stdint.h>

#define S 16384
#define D 4096
#define NE 64
#define CAP 320
#define WQ 4               // waves per block = K-quarters
#define KCH (D / WQ)       // 1024 K per wave
#define KSTEPS (KCH / 16)  // 64 mfma k-steps per wave
#define NKS (D / 16)       // 256 total k-steps
#define K2ROWS 128
#define NB (S / K2ROWS)    // 128

typedef _Float16 f16x8 __attribute__((ext_vector_type(8)));
typedef float f32x16 __attribute__((ext_vector_type(16)));

__device__ __forceinline__ uint32_t rotl32(uint32_t v, int n) {
  return (v << n) | (v >> (32 - n));
}

// Bit-exact jax threefry for jax.random.uniform(jax.random.key(1), (S,), f32)
// under jax_threefry_partitionable=True (default since JAX 0.5.0).
// (Verified passing, absmax 0.0.)
__device__ uint32_t threefry_bits(int i) {
  const uint32_t k0 = 0u, k1 = 1u;
  const uint32_t ks2 = k0 ^ k1 ^ 0x1BD11BDAu;
  uint32_t x0 = 0u + k0;
  uint32_t x1 = (uint32_t)i + k1;
#define TFR(R) { x0 += x1; x1 = rotl32(x1, R); x1 ^= x0; }
  TFR(13) TFR(15) TFR(26) TFR(6)
  x0 += k1;  x1 += ks2 + 1u;
  TFR(17) TFR(29) TFR(16) TFR(24)
  x0 += ks2; x1 += k0 + 2u;
  TFR(13) TFR(15) TFR(26) TFR(6)
  x0 += k0;  x1 += k1 + 3u;
  TFR(17) TFR(29) TFR(16) TFR(24)
  x0 += k1;  x1 += ks2 + 4u;
  TFR(13) TFR(15) TFR(26) TFR(6)
  x0 += ks2; x1 += k0 + 5u;
#undef TFR
  return x0 ^ x1;
}

// ---- k0: pack W (64x4096 f32) into fp16 hi/lo MFMA B-fragments.
// (unchanged from the bit-exact round-2 version)
__global__ __launch_bounds__(256) void k0_packw(const float* __restrict__ Wg,
                                                f16x8* __restrict__ WH,
                                                f16x8* __restrict__ WL) {
  const int tid = blockIdx.x * 256 + threadIdx.x;  // 32768 = 256 ks * 2 t * 64 lanes
  const int lane = tid & 63;
  const int t = (tid >> 6) & 1;
  const int ks = tid >> 7;
  const int col = 32 * t + (lane & 31);
  const int k0 = ks * 16 + 8 * (lane >> 5);
  const float* wp = Wg + (size_t)col * D + k0;
  f16x8 h, l;
#pragma unroll
  for (int j = 0; j < 8; ++j) {
    const float w = wp[j];
    const _Float16 wh = (_Float16)w;
    const float r = (w - (float)wh) * 4096.0f;  // exact in f32
    h[j] = wh;
    l[j] = (_Float16)r;
  }
  WH[tid] = h;
  WL[tid] = l;
}

// ---- k1: fused logits GEMM + softmax + top-2 + RNG.
// Identical arithmetic to the bit-exact round-2 version; only the memory
// pipeline changed: 3-deep x prefetch (use-to-issue ~3 iters vs ~900cy HBM
// latency) and 2-deep B-fragment prefetch (vs ~200-400cy L2 latency).
// Occupancy is pinned at 2 waves/SIMD by the 64-VGPR accumulator set, so
// ILP depth is the only latency lever. Named-slot rotation (no runtime
// array indices -> no scratch). launch_bounds(256,2) = 256-VGPR budget.
struct XS { float4 a, b; };
struct BS { f16x8 h0, h1, l0, l1; };

__global__ __launch_bounds__(256, 2) void k1_fused(const float* __restrict__ x,
                                                   const f16x8* __restrict__ WH,
                                                   const f16x8* __restrict__ WL,
                                                   int* __restrict__ E1, int* __restrict__ E2,
                                                   int* __restrict__ WANT,
                                                   float* __restrict__ G1, float* __restrict__ G2) {
  __shared__ float lsum[WQ][32][64];  // 32 KB
  const int w = threadIdx.x >> 6;     // K-quarter
  const int lane = threadIdx.x & 63;
  const int rowBase = blockIdx.x * 32;
  const int row = rowBase + (lane & 31);
  const float* xp = x + (size_t)row * D + w * KCH + (lane >> 5) * 8;
  const int ks0 = w * KSTEPS;

  f32x16 acc0[2], acc1[2];
#pragma unroll
  for (int t = 0; t < 2; ++t)
#pragma unroll
    for (int r = 0; r < 16; ++r) { acc0[t][r] = 0.0f; acc1[t][r] = 0.0f; }

  auto LDX = [&](int s) {
    XS r;
    r.a = *(const float4*)(xp + s * 16);
    r.b = *(const float4*)(xp + s * 16 + 4);
    return r;
  };
  auto LDB = [&](int s) {
    const size_t fi = (size_t)(ks0 + s) * 128 + lane;
    BS r;
    r.h0 = WH[fi];
    r.h1 = WH[fi + 64];
    r.l0 = WL[fi];
    r.l1 = WL[fi + 64];
    return r;
  };

  XS X0 = LDX(0), X1 = LDX(1), X2 = LDX(2);
  BS B0 = LDB(0), B1 = LDB(1);

  auto body = [&](int xs, int bs) {
    XS Xn = LDX(xs);   // issue deepest-latency load first
    BS Bn = LDB(bs);
    const float af[8] = {X0.a.x, X0.a.y, X0.a.z, X0.a.w,
                         X0.b.x, X0.b.y, X0.b.z, X0.b.w};
    f16x8 ah, al;
#pragma unroll
    for (int j = 0; j < 8; ++j) {
      const _Float16 h = (_Float16)af[j];
      ah[j] = h;
      al[j] = (_Float16)((af[j] - (float)h) * 4096.0f);
    }
    acc0[0] = __builtin_amdgcn_mfma_f32_32x32x16_f16(ah, B0.h0, acc0[0], 0, 0, 0);
    acc1[0] = __builtin_amdgcn_mfma_f32_32x32x16_f16(al, B0.h0, acc1[0], 0, 0, 0);
    acc1[0] = __builtin_amdgcn_mfma_f32_32x32x16_f16(ah, B0.l0, acc1[0], 0, 0, 0);
    acc0[1] = __builtin_amdgcn_mfma_f32_32x32x16_f16(ah, B0.h1, acc0[1], 0, 0, 0);
    acc1[1] = __builtin_amdgcn_mfma_f32_32x32x16_f16(al, B0.h1, acc1[1], 0, 0, 0);
    acc1[1] = __builtin_amdgcn_mfma_f32_32x32x16_f16(ah, B0.l1, acc1[1], 0, 0, 0);
    X0 = X1; X1 = X2; X2 = Xn;
    B0 = B1; B1 = Bn;
  };

#pragma unroll 4
  for (int s = 0; s < KSTEPS - 3; ++s) body(s + 3, s + 2);  // unclamped prefetch
  body(KSTEPS - 1, KSTEPS - 1);  // tail: re-load last frags (harmless)
  body(KSTEPS - 1, KSTEPS - 1);
  body(KSTEPS - 1, KSTEPS - 1);

  // C/D layout (HW-verified m74/m101): col = 32t+(lane&31),
  // row = (reg&3) + 8*(reg>>2) + 4*(lane>>5).
#pragma unroll
  for (int t = 0; t < 2; ++t) {
    const int col = 32 * t + (lane & 31);
#pragma unroll
    for (int r = 0; r < 16; ++r) {
      const int lrow = (r & 3) + 8 * (r >> 2) + 4 * (lane >> 5);
      lsum[w][lrow][col] = acc0[t][r] + acc1[t][r] * (1.0f / 4096.0f);
    }
  }
  __syncthreads();

  // Reduce quarters into plane 0, deterministic order ((q0+q1)+q2)+q3.
  {
    float* p0 = &lsum[0][0][0];
    const float* p1 = &lsum[1][0][0];
    const float* p2 = &lsum[2][0][0];
    const float* p3 = &lsum[3][0][0];
#pragma unroll
    for (int j = 0; j < 8; ++j) {
      const int idx = threadIdx.x + 256 * j;
      p0[idx] = ((p0[idx] + p1[idx]) + p2[idx]) + p3[idx];
    }
  }
  __syncthreads();

  // Softmax + top-2 + RNG (bit-exact logic, unchanged).
  for (int rr = 0; rr < 8; ++rr) {
    const int lrow = w * 8 + rr;
    const int grow = rowBase + lrow;
    const float l = lsum[0][lrow][lane];

    float m = l;
#pragma unroll
    for (int off = 32; off; off >>= 1) m = fmaxf(m, __shfl_xor(m, off));
    const float ex = expf(l - m);
    float ssum = ex;
#pragma unroll
    for (int off = 32; off; off >>= 1) ssum += __shfl_xor(ssum, off);
    ssum = __shfl(ssum, 0);  // single denominator like the reference
    const float gate = ex / ssum;

    float v = gate; int id = lane;
#pragma unroll
    for (int off = 32; off; off >>= 1) {
      float vo = __shfl_xor(v, off); int io = __shfl_xor(id, off);
      if (vo > v || (vo == v && io < id)) { v = vo; id = io; }
    }
    const float g1 = v; const int e1 = id;
    const float gate2 = (lane == e1) ? -1.0f : gate;
    v = gate2; id = lane;
#pragma unroll
    for (int off = 32; off; off >>= 1) {
      float vo = __shfl_xor(v, off); int io = __shfl_xor(id, off);
      if (vo > v || (vo == v && io < id)) { v = vo; id = io; }
    }
    const float g2 = v; const int e2 = id;

    if (lane == 0) {
      const float denom = g1 + g2;
      const float g1n = g1 / denom;
      const float g2n = g2 / denom;
      const uint32_t bits = threefry_bits(grow);
      const float rnd = __uint_as_float((bits >> 9) | 0x3f800000u) - 1.0f;
      E1[grow] = e1; E2[grow] = e2;
      WANT[grow] = (rnd < 2.0f * g2n) ? 1 : 0;
      G1[grow] = g1n; G2[grow] = g2n;
    }
  }
}

// ---- K2: per-block (128 rows) local ranks + histograms (unchanged).
__global__ __launch_bounds__(K2ROWS) void k2_rank(const int* __restrict__ E1,
                                                  const int* __restrict__ E2,
                                                  const int* __restrict__ WANT,
                                                  int* __restrict__ LR1, int* __restrict__ LR2,
                                                  int* __restrict__ H1, int* __restrict__ H2) {
  __shared__ unsigned char s1[K2ROWS], s2[K2ROWS];
  __shared__ int h1[NE], h2[NE];
  const int b = blockIdx.x, t = threadIdx.x;
  const int r = b * K2ROWS + t;
  if (t < NE) { h1[t] = 0; h2[t] = 0; }
  const int e1 = E1[r];
  const int e2 = WANT[r] ? E2[r] : NE;  // sentinel = excluded
  s1[t] = (unsigned char)e1;
  s2[t] = (unsigned char)e2;
  __syncthreads();
  int r1 = 0, r2 = 0;
  for (int j = 0; j < t; ++j) {
    r1 += (s1[j] == e1);
    r2 += (s2[j] == e2);
  }
  LR1[r] = r1; LR2[r] = r2;
  atomicAdd(&h1[e1], 1);
  if (e2 < NE) atomicAdd(&h2[e2], 1);
  __syncthreads();
  if (t < NE) { H1[b * NE + t] = h1[t]; H2[b * NE + t] = h2[t]; }
}

// ---- K3: prefix over blocks per expert. LDS-staged: coalesced int4 bulk
// load (replaces 128 dependent ~400cy global loads per expert with LDS-
// latency chain). Same arithmetic/order as before.
__global__ __launch_bounds__(256) void k3_prefix(const int* __restrict__ H1,
                                                 const int* __restrict__ H2,
                                                 int* __restrict__ OFF1, int* __restrict__ OFF2,
                                                 int* __restrict__ REM2) {
  __shared__ int sh1[NB * NE], sh2[NB * NE];  // 32 KB + 32 KB
  const int t = threadIdx.x;
#pragma unroll
  for (int j = 0; j < 8; ++j) {
    const int i4 = t + 256 * j;  // 2048 int4 = 8192 ints
    ((int4*)sh1)[i4] = ((const int4*)H1)[i4];
    ((int4*)sh2)[i4] = ((const int4*)H2)[i4];
  }
  __syncthreads();
  if (t < NE) {
    int run1 = 0, run2 = 0;
    for (int b = 0; b < NB; ++b) {
      OFF1[b * NE + t] = run1; run1 += sh1[b * NE + t];
      OFF2[b * NE + t] = run2; run2 += sh2[b * NE + t];
    }
    REM2[t] = CAP - min(run1, CAP);
  }
}

// ---- K4: dense writer — lane = expert column, writes every out element
// (zeros included). Replaces memset dispatch + scatter RMW. Logic equals
// memset-to-0 + the verified scatter: slot e1 = keep1?g1n:0, slot e2 =
// keep2?g2n:0 (e1 != e2 always since top-2 distinct), rest 0.
__global__ __launch_bounds__(256) void k4_write(const int* __restrict__ E1,
                                                const int* __restrict__ E2,
                                                const int* __restrict__ WANT,
                                                const float* __restrict__ G1,
                                                const float* __restrict__ G2,
                                                const int* __restrict__ LR1,
                                                const int* __restrict__ LR2,
                                                const int* __restrict__ OFF1,
                                                const int* __restrict__ OFF2,
                                                const int* __restrict__ REM2,
                                                float* __restrict__ out) {
  const int w = threadIdx.x >> 6, lane = threadIdx.x & 63;
  const int rowBase = blockIdx.x * 16 + w * 4;  // grid 1024, 4 rows/wave
#pragma unroll
  for (int i = 0; i < 4; ++i) {
    const int r = rowBase + i;
    const int b = r / K2ROWS;
    const int e1 = E1[r];
    const int pos1 = OFF1[b * NE + e1] + LR1[r] + 1;
    float val = 0.0f;
    if (lane == e1 && pos1 <= CAP) val = G1[r];
    if (WANT[r]) {
      const int e2 = E2[r];
      const int pos2 = OFF2[b * NE + e2] + LR2[r] + 1;
      if (lane == e2 && pos2 <= REM2[e2]) val = G2[r];
    }
    out[(size_t)r * NE + lane] = val;
  }
}

extern "C" void kernel_launch(void* const* d_in, const int* in_sizes, int n_in,
                              void* d_out, int out_size, void* d_ws, size_t ws_size,
                              hipStream_t stream) {
  const float* x  = (const float*)d_in[0];
  const float* Wg = (const float*)d_in[1];
  float* out = (float*)d_out;
  char* ws = (char*)d_ws;

  size_t off = 0;
  int*   E1   = (int*)(ws + off);   off += (size_t)S * 4;
  int*   E2   = (int*)(ws + off);   off += (size_t)S * 4;
  int*   WANT = (int*)(ws + off);   off += (size_t)S * 4;
  float* G1   = (float*)(ws + off); off += (size_t)S * 4;
  float* G2   = (float*)(ws + off); off += (size_t)S * 4;
  int*   LR1  = (int*)(ws + off);   off += (size_t)S * 4;
  int*   LR2  = (int*)(ws + off);   off += (size_t)S * 4;
  int*   H1   = (int*)(ws + off);   off += (size_t)NB * NE * 4;
  int*   H2   = (int*)(ws + off);   off += (size_t)NB * NE * 4;
  int*   OFF1 = (int*)(ws + off);   off += (size_t)NB * NE * 4;
  int*   OFF2 = (int*)(ws + off);   off += (size_t)NB * NE * 4;
  int*   REM2 = (int*)(ws + off);   off += (size_t)NE * 4;
  f16x8* WH   = (f16x8*)(ws + off); off += (size_t)NKS * 2 * 64 * sizeof(f16x8);  // 512 KB
  f16x8* WL   = (f16x8*)(ws + off); off += (size_t)NKS * 2 * 64 * sizeof(f16x8);  // 512 KB

  k0_packw<<<128, 256, 0, stream>>>(Wg, WH, WL);
  k1_fused<<<S / 32, 256, 0, stream>>>(x, WH, WL, E1, E2, WANT, G1, G2);
  k2_rank<<<NB, K2ROWS, 0, stream>>>(E1, E2, WANT, LR1, LR2, H1, H2);
  k3_prefix<<<1, 256, 0, stream>>>(H1, H2, OFF1, OFF2, REM2);
  k4_write<<<S / 16, 256, 0, stream>>>(E1, E2, WANT, G1, G2, LR1, LR2, OFF1, OFF2, REM2, out);
}

// Round 4
// 395.760 us; speedup vs baseline: 1.2072x; 1.2072x over previous
//
#include <hip/hip_runtime.h>
#include <stdint.h>

#define S 16384
#define D 4096
#define NE 64
#define CAP 320
#define WQ 8               // waves per block = K-eighths
#define KCH (D / WQ)       // 512 K per wave
#define KSTEPS (KCH / 16)  // 32 mfma k-steps per wave
#define NKS (D / 16)       // 256 total k-steps
#define K2ROWS 128
#define NB (S / K2ROWS)    // 128

typedef _Float16 f16x8 __attribute__((ext_vector_type(8)));
typedef float f32x16 __attribute__((ext_vector_type(16)));

__device__ __forceinline__ uint32_t rotl32(uint32_t v, int n) {
  return (v << n) | (v >> (32 - n));
}

// Bit-exact jax threefry for jax.random.uniform(jax.random.key(1), (S,), f32)
// under jax_threefry_partitionable=True. (Verified passing, absmax 0.0.)
__device__ uint32_t threefry_bits(int i) {
  const uint32_t k0 = 0u, k1 = 1u;
  const uint32_t ks2 = k0 ^ k1 ^ 0x1BD11BDAu;
  uint32_t x0 = 0u + k0;
  uint32_t x1 = (uint32_t)i + k1;
#define TFR(R) { x0 += x1; x1 = rotl32(x1, R); x1 ^= x0; }
  TFR(13) TFR(15) TFR(26) TFR(6)
  x0 += k1;  x1 += ks2 + 1u;
  TFR(17) TFR(29) TFR(16) TFR(24)
  x0 += ks2; x1 += k0 + 2u;
  TFR(13) TFR(15) TFR(26) TFR(6)
  x0 += k0;  x1 += k1 + 3u;
  TFR(17) TFR(29) TFR(16) TFR(24)
  x0 += k1;  x1 += ks2 + 4u;
  TFR(13) TFR(15) TFR(26) TFR(6)
  x0 += ks2; x1 += k0 + 5u;
#undef TFR
  return x0 ^ x1;
}

// ---- k0: pack W (64x4096 f32) into fp16 hi/lo MFMA B-fragments (unchanged,
// verified bit-exact). Fragment: n-tile t, k-step ks: lane l holds
// col = 32t+(l&31), k = 16*ks + 8*(l>>5) + j. A uses the same k-bijection.
// Split: w = wh + wl*2^-12, wh = fp16(w), wl = fp16((w - wh)*4096).
__global__ __launch_bounds__(256) void k0_packw(const float* __restrict__ Wg,
                                                f16x8* __restrict__ WH,
                                                f16x8* __restrict__ WL) {
  const int tid = blockIdx.x * 256 + threadIdx.x;  // 32768 = 256 ks * 2 t * 64 lanes
  const int lane = tid & 63;
  const int t = (tid >> 6) & 1;
  const int ks = tid >> 7;
  const int col = 32 * t + (lane & 31);
  const int k0 = ks * 16 + 8 * (lane >> 5);
  const float* wp = Wg + (size_t)col * D + k0;
  f16x8 h, l;
#pragma unroll
  for (int j = 0; j < 8; ++j) {
    const float w = wp[j];
    const _Float16 wh = (_Float16)w;
    const float r = (w - (float)wh) * 4096.0f;  // exact in f32
    h[j] = wh;
    l[j] = (_Float16)r;
  }
  WH[tid] = h;
  WL[tid] = l;
}

// ---- k1: fused logits GEMM + softmax + top-2 + RNG.
// Round-2's proven inner loop (simple 1-deep clamped prefetch; compiler
// schedules B loads -- explicit deep pipelining regressed 1.4x in round 3,
// VGPR=48 showed the compiler dropped the pipeline regs). TLP doubled:
// 8 waves/block over the SAME 32 rows, wave w owns K-chunk w (512 K).
// Grid 512 x 512thr = 2 blocks/CU = 16 waves/CU (50% occ; was 8, 20%).
// LDS 64 KB/block -> still 2 blocks/CU. launch_bounds(512,4): 128 VGPR cap,
// measured need ~112 (48 arch + 64 acc).
__global__ __launch_bounds__(512, 4) void k1_fused(const float* __restrict__ x,
                                                   const f16x8* __restrict__ WH,
                                                   const f16x8* __restrict__ WL,
                                                   int* __restrict__ E1, int* __restrict__ E2,
                                                   int* __restrict__ WANT,
                                                   float* __restrict__ G1, float* __restrict__ G2) {
  __shared__ float lsum[WQ][32][64];  // 64 KB
  const int w = threadIdx.x >> 6;     // K-eighth 0..7
  const int lane = threadIdx.x & 63;
  const int rowBase = blockIdx.x * 32;
  const int row = rowBase + (lane & 31);
  // A fragment source: lane holds x[row][kOff + 16*s + 8*(lane>>5) + j]
  const float* xp = x + (size_t)row * D + w * KCH + (lane >> 5) * 8;
  const int ks0 = w * KSTEPS;

  f32x16 acc0[2], acc1[2];
#pragma unroll
  for (int t = 0; t < 2; ++t)
#pragma unroll
    for (int r = 0; r < 16; ++r) { acc0[t][r] = 0.0f; acc1[t][r] = 0.0f; }

  float4 a0 = *(const float4*)(xp);
  float4 a1 = *(const float4*)(xp + 4);
#pragma unroll 2
  for (int s = 0; s < KSTEPS; ++s) {
    const int sn = (s + 1 < KSTEPS) ? s + 1 : s;  // clamped prefetch (no OOB)
    const float4 a0n = *(const float4*)(xp + sn * 16);
    const float4 a1n = *(const float4*)(xp + sn * 16 + 4);
    const size_t fi = (size_t)(ks0 + s) * 128 + lane;
    const f16x8 bh0 = WH[fi];
    const f16x8 bh1 = WH[fi + 64];
    const f16x8 bl0 = WL[fi];
    const f16x8 bl1 = WL[fi + 64];

    const float af[8] = {a0.x, a0.y, a0.z, a0.w, a1.x, a1.y, a1.z, a1.w};
    f16x8 ah, al;
#pragma unroll
    for (int j = 0; j < 8; ++j) {
      const _Float16 h = (_Float16)af[j];
      ah[j] = h;
      al[j] = (_Float16)((af[j] - (float)h) * 4096.0f);
    }

    acc0[0] = __builtin_amdgcn_mfma_f32_32x32x16_f16(ah, bh0, acc0[0], 0, 0, 0);
    acc1[0] = __builtin_amdgcn_mfma_f32_32x32x16_f16(al, bh0, acc1[0], 0, 0, 0);
    acc1[0] = __builtin_amdgcn_mfma_f32_32x32x16_f16(ah, bl0, acc1[0], 0, 0, 0);
    acc0[1] = __builtin_amdgcn_mfma_f32_32x32x16_f16(ah, bh1, acc0[1], 0, 0, 0);
    acc1[1] = __builtin_amdgcn_mfma_f32_32x32x16_f16(al, bh1, acc1[1], 0, 0, 0);
    acc1[1] = __builtin_amdgcn_mfma_f32_32x32x16_f16(ah, bl1, acc1[1], 0, 0, 0);

    a0 = a0n; a1 = a1n;
  }

  // C/D layout (HW-verified m74/m101): col = 32t+(lane&31),
  // row = (reg&3) + 8*(reg>>2) + 4*(lane>>5).
#pragma unroll
  for (int t = 0; t < 2; ++t) {
    const int col = 32 * t + (lane & 31);
#pragma unroll
    for (int r = 0; r < 16; ++r) {
      const int lrow = (r & 3) + 8 * (r >> 2) + 4 * (lane >> 5);
      lsum[w][lrow][col] = acc0[t][r] + acc1[t][r] * (1.0f / 4096.0f);
    }
  }
  __syncthreads();

  // Reduce 8 planes into plane 0, deterministic left fold.
  {
    float* p0 = &lsum[0][0][0];
#pragma unroll
    for (int j = 0; j < 4; ++j) {
      const int idx = threadIdx.x + 512 * j;  // 2048 idx, consecutive banks
      float v = p0[idx];
#pragma unroll
      for (int q = 1; q < WQ; ++q) v += (&lsum[0][0][0])[q * 2048 + idx];
      p0[idx] = v;
    }
  }
  __syncthreads();

  // Softmax + top-2 + RNG (bit-exact logic, unchanged). Wave w: rows 4w..4w+3.
  for (int rr = 0; rr < 4; ++rr) {
    const int lrow = w * 4 + rr;
    const int grow = rowBase + lrow;
    const float l = lsum[0][lrow][lane];

    float m = l;
#pragma unroll
    for (int off = 32; off; off >>= 1) m = fmaxf(m, __shfl_xor(m, off));
    const float ex = expf(l - m);
    float ssum = ex;
#pragma unroll
    for (int off = 32; off; off >>= 1) ssum += __shfl_xor(ssum, off);
    ssum = __shfl(ssum, 0);  // single denominator like the reference
    const float gate = ex / ssum;

    float v = gate; int id = lane;
#pragma unroll
    for (int off = 32; off; off >>= 1) {
      float vo = __shfl_xor(v, off); int io = __shfl_xor(id, off);
      if (vo > v || (vo == v && io < id)) { v = vo; id = io; }
    }
    const float g1 = v; const int e1 = id;
    const float gate2 = (lane == e1) ? -1.0f : gate;
    v = gate2; id = lane;
#pragma unroll
    for (int off = 32; off; off >>= 1) {
      float vo = __shfl_xor(v, off); int io = __shfl_xor(id, off);
      if (vo > v || (vo == v && io < id)) { v = vo; id = io; }
    }
    const float g2 = v; const int e2 = id;

    if (lane == 0) {
      const float denom = g1 + g2;
      const float g1n = g1 / denom;
      const float g2n = g2 / denom;
      const uint32_t bits = threefry_bits(grow);
      const float rnd = __uint_as_float((bits >> 9) | 0x3f800000u) - 1.0f;
      E1[grow] = e1; E2[grow] = e2;
      WANT[grow] = (rnd < 2.0f * g2n) ? 1 : 0;
      G1[grow] = g1n; G2[grow] = g2n;
    }
  }
}

// ---- K2: per-block (128 rows) local ranks + histograms (unchanged).
__global__ __launch_bounds__(K2ROWS) void k2_rank(const int* __restrict__ E1,
                                                  const int* __restrict__ E2,
                                                  const int* __restrict__ WANT,
                                                  int* __restrict__ LR1, int* __restrict__ LR2,
                                                  int* __restrict__ H1, int* __restrict__ H2) {
  __shared__ unsigned char s1[K2ROWS], s2[K2ROWS];
  __shared__ int h1[NE], h2[NE];
  const int b = blockIdx.x, t = threadIdx.x;
  const int r = b * K2ROWS + t;
  if (t < NE) { h1[t] = 0; h2[t] = 0; }
  const int e1 = E1[r];
  const int e2 = WANT[r] ? E2[r] : NE;  // sentinel = excluded
  s1[t] = (unsigned char)e1;
  s2[t] = (unsigned char)e2;
  __syncthreads();
  int r1 = 0, r2 = 0;
  for (int j = 0; j < t; ++j) {
    r1 += (s1[j] == e1);
    r2 += (s2[j] == e2);
  }
  LR1[r] = r1; LR2[r] = r2;
  atomicAdd(&h1[e1], 1);
  if (e2 < NE) atomicAdd(&h2[e2], 1);
  __syncthreads();
  if (t < NE) { H1[b * NE + t] = h1[t]; H2[b * NE + t] = h2[t]; }
}

// ---- K3: prefix over blocks per expert, LDS-staged (verified round 3).
__global__ __launch_bounds__(256) void k3_prefix(const int* __restrict__ H1,
                                                 const int* __restrict__ H2,
                                                 int* __restrict__ OFF1, int* __restrict__ OFF2,
                                                 int* __restrict__ REM2) {
  __shared__ int sh1[NB * NE], sh2[NB * NE];  // 32 KB + 32 KB
  const int t = threadIdx.x;
#pragma unroll
  for (int j = 0; j < 8; ++j) {
    const int i4 = t + 256 * j;  // 2048 int4 = 8192 ints
    ((int4*)sh1)[i4] = ((const int4*)H1)[i4];
    ((int4*)sh2)[i4] = ((const int4*)H2)[i4];
  }
  __syncthreads();
  if (t < NE) {
    int run1 = 0, run2 = 0;
    for (int b = 0; b < NB; ++b) {
      OFF1[b * NE + t] = run1; run1 += sh1[b * NE + t];
      OFF2[b * NE + t] = run2; run2 += sh2[b * NE + t];
    }
    REM2[t] = CAP - min(run1, CAP);
  }
}

// ---- K4: dense writer, lane = expert column (verified round 3).
__global__ __launch_bounds__(256) void k4_write(const int* __restrict__ E1,
                                                const int* __restrict__ E2,
                                                const int* __restrict__ WANT,
                                                const float* __restrict__ G1,
                                                const float* __restrict__ G2,
                                                const int* __restrict__ LR1,
                                                const int* __restrict__ LR2,
                                                const int* __restrict__ OFF1,
                                                const int* __restrict__ OFF2,
                                                const int* __restrict__ REM2,
                                                float* __restrict__ out) {
  const int w = threadIdx.x >> 6, lane = threadIdx.x & 63;
  const int rowBase = blockIdx.x * 16 + w * 4;  // grid 1024, 4 rows/wave
#pragma unroll
  for (int i = 0; i < 4; ++i) {
    const int r = rowBase + i;
    const int b = r / K2ROWS;
    const int e1 = E1[r];
    const int pos1 = OFF1[b * NE + e1] + LR1[r] + 1;
    float val = 0.0f;
    if (lane == e1 && pos1 <= CAP) val = G1[r];
    if (WANT[r]) {
      const int e2 = E2[r];
      const int pos2 = OFF2[b * NE + e2] + LR2[r] + 1;
      if (lane == e2 && pos2 <= REM2[e2]) val = G2[r];
    }
    out[(size_t)r * NE + lane] = val;
  }
}

extern "C" void kernel_launch(void* const* d_in, const int* in_sizes, int n_in,
                              void* d_out, int out_size, void* d_ws, size_t ws_size,
                              hipStream_t stream) {
  const float* x  = (const float*)d_in[0];
  const float* Wg = (const float*)d_in[1];
  float* out = (float*)d_out;
  char* ws = (char*)d_ws;

  size_t off = 0;
  int*   E1   = (int*)(ws + off);   off += (size_t)S * 4;
  int*   E2   = (int*)(ws + off);   off += (size_t)S * 4;
  int*   WANT = (int*)(ws + off);   off += (size_t)S * 4;
  float* G1   = (float*)(ws + off); off += (size_t)S * 4;
  float* G2   = (float*)(ws + off); off += (size_t)S * 4;
  int*   LR1  = (int*)(ws + off);   off += (size_t)S * 4;
  int*   LR2  = (int*)(ws + off);   off += (size_t)S * 4;
  int*   H1   = (int*)(ws + off);   off += (size_t)NB * NE * 4;
  int*   H2   = (int*)(ws + off);   off += (size_t)NB * NE * 4;
  int*   OFF1 = (int*)(ws + off);   off += (size_t)NB * NE * 4;
  int*   OFF2 = (int*)(ws + off);   off += (size_t)NB * NE * 4;
  int*   REM2 = (int*)(ws + off);   off += (size_t)NE * 4;
  f16x8* WH   = (f16x8*)(ws + off); off += (size_t)NKS * 2 * 64 * sizeof(f16x8);  // 512 KB
  f16x8* WL   = (f16x8*)(ws + off); off += (size_t)NKS * 2 * 64 * sizeof(f16x8);  // 512 KB

  k0_packw<<<128, 256, 0, stream>>>(Wg, WH, WL);
  k1_fused<<<S / 32, 512, 0, stream>>>(x, WH, WL, E1, E2, WANT, G1, G2);
  k2_rank<<<NB, K2ROWS, 0, stream>>>(E1, E2, WANT, LR1, LR2, H1, H2);
  k3_prefix<<<1, 256, 0, stream>>>(H1, H2, OFF1, OFF2, REM2);
  k4_write<<<S / 16, 256, 0, stream>>>(E1, E2, WANT, G1, G2, LR1, LR2, OFF1, OFF2, REM2, out);
}

// Round 5
// 394.448 us; speedup vs baseline: 1.2112x; 1.0033x over previous
//
#include <hip/hip_runtime.h>
#include <stdint.h>

#define S 16384
#define D 4096
#define NE 64
#define CAP 320
#define WPB 4              // waves per block
#define KSPLIT 8           // K-eighths; wave = one eighth, block = one half
#define KCH (D / KSPLIT)   // 512 K per wave
#define KSTEPS (KCH / 16)  // 32 mfma k-steps per wave
#define NKS (D / 16)       // 256 total k-steps
#define K2ROWS 128
#define NB (S / K2ROWS)    // 128

typedef _Float16 f16x8 __attribute__((ext_vector_type(8)));
typedef float f32x16 __attribute__((ext_vector_type(16)));

__device__ __forceinline__ uint32_t rotl32(uint32_t v, int n) {
  return (v << n) | (v >> (32 - n));
}

// Bit-exact jax threefry for jax.random.uniform(jax.random.key(1), (S,), f32)
// under jax_threefry_partitionable=True. (Verified passing, absmax 0.0.)
__device__ uint32_t threefry_bits(int i) {
  const uint32_t k0 = 0u, k1 = 1u;
  const uint32_t ks2 = k0 ^ k1 ^ 0x1BD11BDAu;
  uint32_t x0 = 0u + k0;
  uint32_t x1 = (uint32_t)i + k1;
#define TFR(R) { x0 += x1; x1 = rotl32(x1, R); x1 ^= x0; }
  TFR(13) TFR(15) TFR(26) TFR(6)
  x0 += k1;  x1 += ks2 + 1u;
  TFR(17) TFR(29) TFR(16) TFR(24)
  x0 += ks2; x1 += k0 + 2u;
  TFR(13) TFR(15) TFR(26) TFR(6)
  x0 += k0;  x1 += k1 + 3u;
  TFR(17) TFR(29) TFR(16) TFR(24)
  x0 += k1;  x1 += ks2 + 4u;
  TFR(13) TFR(15) TFR(26) TFR(6)
  x0 += ks2; x1 += k0 + 5u;
#undef TFR
  return x0 ^ x1;
}

// ---- k0: pack W (64x4096 f32) into fp16 hi/lo MFMA B-fragments (verified).
// n-tile t, k-step ks: lane l holds col = 32t+(l&31), k = 16*ks + 8*(l>>5)+j.
// A uses the same k-bijection. Split: w = wh + wl*2^-12 (exact residual).
__global__ __launch_bounds__(256) void k0_packw(const float* __restrict__ Wg,
                                                f16x8* __restrict__ WH,
                                                f16x8* __restrict__ WL) {
  const int tid = blockIdx.x * 256 + threadIdx.x;  // 32768 = 256 ks * 2 t * 64 lanes
  const int lane = tid & 63;
  const int t = (tid >> 6) & 1;
  const int ks = tid >> 7;
  const int col = 32 * t + (lane & 31);
  const int k0 = ks * 16 + 8 * (lane >> 5);
  const float* wp = Wg + (size_t)col * D + k0;
  f16x8 h, l;
#pragma unroll
  for (int j = 0; j < 8; ++j) {
    const float w = wp[j];
    const _Float16 wh = (_Float16)w;
    const float r = (w - (float)wh) * 4096.0f;  // exact in f32
    h[j] = wh;
    l[j] = (_Float16)r;
  }
  WH[tid] = h;
  WL[tid] = l;
}

// Per-element fp32 -> fp16 hi/lo split (same arithmetic as all passing rounds).
#define CVT1(J, F)                                                     \
  { const float f_ = (F); const _Float16 h_ = (_Float16)f_;            \
    ah[J] = h_; al[J] = (_Float16)((f_ - (float)h_) * 4096.0f); }

// One k-step: convert 8 x-values, 6 MFMAs into flat accumulators.
#define KSTEP(X0, X1, BH0, BH1, BL0, BL1)                                    \
  {                                                                          \
    f16x8 ah, al;                                                            \
    CVT1(0, (X0).x) CVT1(1, (X0).y) CVT1(2, (X0).z) CVT1(3, (X0).w)          \
    CVT1(4, (X1).x) CVT1(5, (X1).y) CVT1(6, (X1).z) CVT1(7, (X1).w)          \
    acc00 = __builtin_amdgcn_mfma_f32_32x32x16_f16(ah, BH0, acc00, 0, 0, 0); \
    acc10 = __builtin_amdgcn_mfma_f32_32x32x16_f16(al, BH0, acc10, 0, 0, 0); \
    acc10 = __builtin_amdgcn_mfma_f32_32x32x16_f16(ah, BL0, acc10, 0, 0, 0); \
    acc01 = __builtin_amdgcn_mfma_f32_32x32x16_f16(ah, BH1, acc01, 0, 0, 0); \
    acc11 = __builtin_amdgcn_mfma_f32_32x32x16_f16(al, BH1, acc11, 0, 0, 0); \
    acc11 = __builtin_amdgcn_mfma_f32_32x32x16_f16(ah, BL1, acc11, 0, 0, 0); \
  }

// ---- k1: logits GEMM partials, latency-tolerant form.
// Block = 4 waves over the SAME 32 rows; blockIdx = (rowgroup, K-half);
// wave w owns K-eighth kh*4+w (512 K, 32 steps). Flat named ping-pong
// double-buffer (no structs/lambdas/arrays -> SSA -> no scratch; rounds 3/4
// showed struct pipelines and tight launch_bounds both force spills).
// No min-waves bound: ~134 unified regs -> 3 blocks/CU = 12 waves/CU,
// grid 1024 = 4/CU available. Partial K-half sums -> part[2][S][64].
__global__ __launch_bounds__(256) void k1_logits(const float* __restrict__ x,
                                                 const f16x8* __restrict__ WH,
                                                 const f16x8* __restrict__ WL,
                                                 float* __restrict__ part) {
  __shared__ float lsum[WPB][32][64];  // 32 KB
  const int w = threadIdx.x >> 6;
  const int lane = threadIdx.x & 63;
  const int rg = blockIdx.x >> 1;   // row group (512)
  const int kh = blockIdx.x & 1;    // K half
  const int rowBase = rg * 32;
  const int row = rowBase + (lane & 31);
  const int kidx = kh * 4 + w;      // K-eighth 0..7
  // A fragment source: lane holds x[row][kidx*512 + 16*s + 8*(lane>>5) + j]
  const float* xp = x + (size_t)row * D + kidx * KCH + (lane >> 5) * 8;
  const float4* xq = (const float4*)xp;
  const int ks0 = kidx * KSTEPS;

  f32x16 acc00, acc01, acc10, acc11;
#pragma unroll
  for (int r = 0; r < 16; ++r) { acc00[r] = 0.0f; acc01[r] = 0.0f; acc10[r] = 0.0f; acc11[r] = 0.0f; }

  // prologue: step 0 into bank A
  float4 xa0 = xq[0], xa1 = xq[1];
  size_t fiA = (size_t)ks0 * 128 + lane;
  f16x8 bha0 = WH[fiA], bha1 = WH[fiA + 64];
  f16x8 bla0 = WL[fiA], bla1 = WL[fiA + 64];

  for (int s = 0; s < KSTEPS; s += 2) {
    // prefetch step s+1 into bank B (KSTEPS even -> always valid)
    const size_t fiB = (size_t)(ks0 + s + 1) * 128 + lane;
    const float4 xb0 = xq[(s + 1) * 4];
    const float4 xb1 = xq[(s + 1) * 4 + 1];
    const f16x8 bhb0 = WH[fiB], bhb1 = WH[fiB + 64];
    const f16x8 blb0 = WL[fiB], blb1 = WL[fiB + 64];

    KSTEP(xa0, xa1, bha0, bha1, bla0, bla1);  // compute step s

    // prefetch step s+2 into bank A (clamped to 0 on last iter; dead loads)
    const int s2 = (s + 2 < KSTEPS) ? (s + 2) : 0;
    const size_t fiA2 = (size_t)(ks0 + s2) * 128 + lane;
    xa0 = xq[s2 * 4]; xa1 = xq[s2 * 4 + 1];
    bha0 = WH[fiA2]; bha1 = WH[fiA2 + 64];
    bla0 = WL[fiA2]; bla1 = WL[fiA2 + 64];

    KSTEP(xb0, xb1, bhb0, bhb1, blb0, blb1);  // compute step s+1
  }

  // C/D layout (HW-verified m74/m101): col = 32t+(lane&31),
  // row = (reg&3) + 8*(reg>>2) + 4*(lane>>5).
#pragma unroll
  for (int r = 0; r < 16; ++r) {
    const int lrow = (r & 3) + 8 * (r >> 2) + 4 * (lane >> 5);
    lsum[w][lrow][lane & 31]        = acc00[r] + acc10[r] * (1.0f / 4096.0f);
    lsum[w][lrow][32 + (lane & 31)] = acc01[r] + acc11[r] * (1.0f / 4096.0f);
  }
  __syncthreads();

  // Fold 4 wave-planes (deterministic ((w0+w1)+w2)+w3) and write the K-half
  // partial. idx = tid + 256*j spans 32x64 row-major -> coalesced.
  {
    const float* p0 = &lsum[0][0][0];
#pragma unroll
    for (int j = 0; j < 8; ++j) {
      const int idx = threadIdx.x + 256 * j;
      const float v = ((p0[idx] + p0[idx + 2048]) + p0[idx + 4096]) + p0[idx + 6144];
      part[((size_t)kh * S + rowBase) * NE + idx] = v;
    }
  }
}

// ---- k1b: reduce K-half partials, softmax, top-2, RNG (round-0/2-verified
// body; c<2). One wave per row, lane = expert.
__global__ __launch_bounds__(256) void k1b_reduce(const float* __restrict__ part,
                                                  int* __restrict__ E1, int* __restrict__ E2,
                                                  int* __restrict__ WANT,
                                                  float* __restrict__ G1, float* __restrict__ G2) {
  const int row = blockIdx.x * 4 + (threadIdx.x >> 6);
  const int lane = threadIdx.x & 63;
  float l = 0.0f;
#pragma unroll
  for (int c = 0; c < 2; ++c)
    l += part[((size_t)c * S + row) * NE + lane];

  float m = l;
#pragma unroll
  for (int off = 32; off; off >>= 1) m = fmaxf(m, __shfl_xor(m, off));
  const float ex = expf(l - m);
  float ssum = ex;
#pragma unroll
  for (int off = 32; off; off >>= 1) ssum += __shfl_xor(ssum, off);
  ssum = __shfl(ssum, 0);  // single denominator like the reference
  const float gate = ex / ssum;

  float v = gate; int id = lane;
#pragma unroll
  for (int off = 32; off; off >>= 1) {
    float vo = __shfl_xor(v, off); int io = __shfl_xor(id, off);
    if (vo > v || (vo == v && io < id)) { v = vo; id = io; }
  }
  const float g1 = v; const int e1 = id;
  const float gate2 = (lane == e1) ? -1.0f : gate;
  v = gate2; id = lane;
#pragma unroll
  for (int off = 32; off; off >>= 1) {
    float vo = __shfl_xor(v, off); int io = __shfl_xor(id, off);
    if (vo > v || (vo == v && io < id)) { v = vo; id = io; }
  }
  const float g2 = v; const int e2 = id;

  if (lane == 0) {
    const float denom = g1 + g2;
    const float g1n = g1 / denom;
    const float g2n = g2 / denom;
    const uint32_t bits = threefry_bits(row);
    const float rnd = __uint_as_float((bits >> 9) | 0x3f800000u) - 1.0f;
    E1[row] = e1; E2[row] = e2;
    WANT[row] = (rnd < 2.0f * g2n) ? 1 : 0;
    G1[row] = g1n; G2[row] = g2n;
  }
}

// ---- K2: per-block (128 rows) local ranks + histograms (unchanged).
__global__ __launch_bounds__(K2ROWS) void k2_rank(const int* __restrict__ E1,
                                                  const int* __restrict__ E2,
                                                  const int* __restrict__ WANT,
                                                  int* __restrict__ LR1, int* __restrict__ LR2,
                                                  int* __restrict__ H1, int* __restrict__ H2) {
  __shared__ unsigned char s1[K2ROWS], s2[K2ROWS];
  __shared__ int h1[NE], h2[NE];
  const int b = blockIdx.x, t = threadIdx.x;
  const int r = b * K2ROWS + t;
  if (t < NE) { h1[t] = 0; h2[t] = 0; }
  const int e1 = E1[r];
  const int e2 = WANT[r] ? E2[r] : NE;  // sentinel = excluded
  s1[t] = (unsigned char)e1;
  s2[t] = (unsigned char)e2;
  __syncthreads();
  int r1 = 0, r2 = 0;
  for (int j = 0; j < t; ++j) {
    r1 += (s1[j] == e1);
    r2 += (s2[j] == e2);
  }
  LR1[r] = r1; LR2[r] = r2;
  atomicAdd(&h1[e1], 1);
  if (e2 < NE) atomicAdd(&h2[e2], 1);
  __syncthreads();
  if (t < NE) { H1[b * NE + t] = h1[t]; H2[b * NE + t] = h2[t]; }
}

// ---- K3: prefix over blocks per expert, LDS-staged (verified round 3).
__global__ __launch_bounds__(256) void k3_prefix(const int* __restrict__ H1,
                                                 const int* __restrict__ H2,
                                                 int* __restrict__ OFF1, int* __restrict__ OFF2,
                                                 int* __restrict__ REM2) {
  __shared__ int sh1[NB * NE], sh2[NB * NE];  // 32 KB + 32 KB
  const int t = threadIdx.x;
#pragma unroll
  for (int j = 0; j < 8; ++j) {
    const int i4 = t + 256 * j;  // 2048 int4 = 8192 ints
    ((int4*)sh1)[i4] = ((const int4*)H1)[i4];
    ((int4*)sh2)[i4] = ((const int4*)H2)[i4];
  }
  __syncthreads();
  if (t < NE) {
    int run1 = 0, run2 = 0;
    for (int b = 0; b < NB; ++b) {
      OFF1[b * NE + t] = run1; run1 += sh1[b * NE + t];
      OFF2[b * NE + t] = run2; run2 += sh2[b * NE + t];
    }
    REM2[t] = CAP - min(run1, CAP);
  }
}

// ---- K4: dense writer, lane = expert column (verified round 3).
__global__ __launch_bounds__(256) void k4_write(const int* __restrict__ E1,
                                                const int* __restrict__ E2,
                                                const int* __restrict__ WANT,
                                                const float* __restrict__ G1,
                                                const float* __restrict__ G2,
                                                const int* __restrict__ LR1,
                                                const int* __restrict__ LR2,
                                                const int* __restrict__ OFF1,
                                                const int* __restrict__ OFF2,
                                                const int* __restrict__ REM2,
                                                float* __restrict__ out) {
  const int w = threadIdx.x >> 6, lane = threadIdx.x & 63;
  const int rowBase = blockIdx.x * 16 + w * 4;  // grid 1024, 4 rows/wave
#pragma unroll
  for (int i = 0; i < 4; ++i) {
    const int r = rowBase + i;
    const int b = r / K2ROWS;
    const int e1 = E1[r];
    const int pos1 = OFF1[b * NE + e1] + LR1[r] + 1;
    float val = 0.0f;
    if (lane == e1 && pos1 <= CAP) val = G1[r];
    if (WANT[r]) {
      const int e2 = E2[r];
      const int pos2 = OFF2[b * NE + e2] + LR2[r] + 1;
      if (lane == e2 && pos2 <= REM2[e2]) val = G2[r];
    }
    out[(size_t)r * NE + lane] = val;
  }
}

extern "C" void kernel_launch(void* const* d_in, const int* in_sizes, int n_in,
                              void* d_out, int out_size, void* d_ws, size_t ws_size,
                              hipStream_t stream) {
  const float* x  = (const float*)d_in[0];
  const float* Wg = (const float*)d_in[1];
  float* out = (float*)d_out;
  char* ws = (char*)d_ws;

  size_t off = 0;
  float* part = (float*)ws;         off += (size_t)2 * S * NE * 4;  // 8 MB
  int*   E1   = (int*)(ws + off);   off += (size_t)S * 4;
  int*   E2   = (int*)(ws + off);   off += (size_t)S * 4;
  int*   WANT = (int*)(ws + off);   off += (size_t)S * 4;
  float* G1   = (float*)(ws + off); off += (size_t)S * 4;
  float* G2   = (float*)(ws + off); off += (size_t)S * 4;
  int*   LR1  = (int*)(ws + off);   off += (size_t)S * 4;
  int*   LR2  = (int*)(ws + off);   off += (size_t)S * 4;
  int*   H1   = (int*)(ws + off);   off += (size_t)NB * NE * 4;
  int*   H2   = (int*)(ws + off);   off += (size_t)NB * NE * 4;
  int*   OFF1 = (int*)(ws + off);   off += (size_t)NB * NE * 4;
  int*   OFF2 = (int*)(ws + off);   off += (size_t)NB * NE * 4;
  int*   REM2 = (int*)(ws + off);   off += (size_t)NE * 4;
  f16x8* WH   = (f16x8*)(ws + off); off += (size_t)NKS * 2 * 64 * sizeof(f16x8);  // 512 KB
  f16x8* WL   = (f16x8*)(ws + off); off += (size_t)NKS * 2 * 64 * sizeof(f16x8);  // 512 KB

  k0_packw<<<128, 256, 0, stream>>>(Wg, WH, WL);
  k1_logits<<<(S / 32) * 2, 256, 0, stream>>>(x, WH, WL, part);
  k1b_reduce<<<S / 4, 256, 0, stream>>>(part, E1, E2, WANT, G1, G2);
  k2_rank<<<NB, K2ROWS, 0, stream>>>(E1, E2, WANT, LR1, LR2, H1, H2);
  k3_prefix<<<1, 256, 0, stream>>>(H1, H2, OFF1, OFF2, REM2);
  k4_write<<<S / 16, 256, 0, stream>>>(E1, E2, WANT, G1, G2, LR1, LR2, OFF1, OFF2, REM2, out);
}